// Round 1
// 468.115 us; speedup vs baseline: 1.2136x; 1.2136x over previous
//
#include <hip/hip_runtime.h>
#include <hip/hip_bf16.h>

#define B_ 2
#define C_ 192
#define HEADS_ 8
#define CH_ 24
#define H_ 256
#define W_ 256
#define HW_ 65536

// ---------------- workspace layout (bytes) ----------------
// tmpQ  bf16 [B][192][HW]   @ 0           (50331648)   } tmpV aliases tmpQ
// tmpKV bf16 [B][384][HW]   @ 50331648    (100663296)  } (K3 consumes tmpQ first)
// G     f32  [B][8][24][24] @ 150994944   (36864)
// sq    f32  [B][192]       @ 151031808   (1536)
// sk    f32  [B][192]       @ 151033344   (1536)
// M     f32  [B][192][192]  @ 151034880   (294912)

using bf16x8 = __attribute__((ext_vector_type(8))) __bf16;
using f32x4  = __attribute__((ext_vector_type(4))) float;

__device__ __forceinline__ float b2f_us(unsigned short u) {
    return __uint_as_float(((unsigned)u) << 16);
}
__device__ __forceinline__ unsigned short f2bf(float f) {
    union { __hip_bfloat16 b; unsigned short u; } cv;
    cv.b = __float2bfloat16(f);
    return cv.u;
}

// ---------------------------------------------------------------------------
// MFMA GEMM: Out[o, n] = sum_k A[o, k] * B[k, n];  K = 192, N-tile = 64,
// M-tile = 192 (4 waves x 48 rows). A fp32 (-> bf16 in staging). B either
// fp32 (x / x_ref) or bf16 (tmpV). Out either bf16 (tmpQ/tmpKV) or f32 (out).
// LDS: Al[o][k] pitch 40 bf16; Bl[rB][k] pitch 40, rB = ((p&3)<<4)|(p>>2)
// so lane li's 4 n-frags are pixels 4*li .. 4*li+3 (contiguous epilogue).
// ---------------------------------------------------------------------------
template<bool B_F32, bool OUT_F32>
__global__ __launch_bounds__(256) void gemm_mfma(
    const float* __restrict__ A, long a_bstride,
    const void* __restrict__ Bv, void* __restrict__ Outv, int outC)
{
    const int nb = blockIdx.x * 64;
    const int mt = blockIdx.y;
    const int b  = blockIdx.z;
    const int t  = threadIdx.x;

    __shared__ unsigned short Al[192 * 40];
    __shared__ unsigned short Bl[64 * 40];

    const float* Ab = A + (size_t)b * a_bstride + (size_t)mt * 192 * 192;

    const int w = t >> 6, l = t & 63, li = l & 15, q = l >> 4;

    f32x4 acc[3][4];
#pragma unroll
    for (int mi = 0; mi < 3; mi++)
#pragma unroll
        for (int ni = 0; ni < 4; ni++)
            acc[mi][ni] = (f32x4){0.f, 0.f, 0.f, 0.f};

    const int p0 = (t & 15) * 4;   // B staging: pixel group
    const int kp = t >> 4;         // B staging: k-pair index (0..15)

    for (int kc = 0; kc < 6; kc++) {
        const int k0 = kc * 32;

        // ---- stage A chunk: 192 x 32 fp32 -> bf16 ----
#pragma unroll
        for (int j = 0; j < 6; j++) {
            int e = t + 256 * j;
            int o = e >> 3, kq = e & 7;
            float4 va = *(const float4*)(Ab + (size_t)o * 192 + k0 + kq * 4);
            ushort4 u;
            u.x = f2bf(va.x); u.y = f2bf(va.y); u.z = f2bf(va.z); u.w = f2bf(va.w);
            *(ushort4*)&Al[o * 40 + kq * 4] = u;
        }

        // ---- stage B chunk: 32 x 64, transposed into Bl[rB][k] ----
        {
            const int k = k0 + kp * 2;
            unsigned int packed[4];
            if (B_F32) {
                const float* Bb = (const float*)Bv + (size_t)b * 192 * HW_;
                float4 r0 = *(const float4*)(Bb + (size_t)k * HW_ + nb + p0);
                float4 r1 = *(const float4*)(Bb + (size_t)(k + 1) * HW_ + nb + p0);
                packed[0] = (unsigned)f2bf(r0.x) | ((unsigned)f2bf(r1.x) << 16);
                packed[1] = (unsigned)f2bf(r0.y) | ((unsigned)f2bf(r1.y) << 16);
                packed[2] = (unsigned)f2bf(r0.z) | ((unsigned)f2bf(r1.z) << 16);
                packed[3] = (unsigned)f2bf(r0.w) | ((unsigned)f2bf(r1.w) << 16);
            } else {
                const unsigned short* Bb = (const unsigned short*)Bv + (size_t)b * 192 * HW_;
                ushort4 r0 = *(const ushort4*)(Bb + (size_t)k * HW_ + nb + p0);
                ushort4 r1 = *(const ushort4*)(Bb + (size_t)(k + 1) * HW_ + nb + p0);
                packed[0] = (unsigned)r0.x | ((unsigned)r1.x << 16);
                packed[1] = (unsigned)r0.y | ((unsigned)r1.y << 16);
                packed[2] = (unsigned)r0.z | ((unsigned)r1.z << 16);
                packed[3] = (unsigned)r0.w | ((unsigned)r1.w << 16);
            }
#pragma unroll
            for (int c = 0; c < 4; c++) {
                int p = p0 + c;
                int rB = ((p & 3) << 4) | (p >> 2);
                *(unsigned int*)&Bl[rB * 40 + kp * 2] = packed[c];
            }
        }
        __syncthreads();

        // ---- fragments + MFMA ----
        bf16x8 af[3], bfr[4];
#pragma unroll
        for (int mi = 0; mi < 3; mi++)
            af[mi] = *(const bf16x8*)&Al[(w * 48 + mi * 16 + li) * 40 + q * 8];
#pragma unroll
        for (int ni = 0; ni < 4; ni++)
            bfr[ni] = *(const bf16x8*)&Bl[(ni * 16 + li) * 40 + q * 8];
#pragma unroll
        for (int mi = 0; mi < 3; mi++)
#pragma unroll
            for (int ni = 0; ni < 4; ni++)
                acc[mi][ni] = __builtin_amdgcn_mfma_f32_16x16x32_bf16(
                    af[mi], bfr[ni], acc[mi][ni], 0, 0, 0);
        __syncthreads();
    }

    // ---- epilogue: lane li holds pixels nb+4*li .. +3 (regs ni), rows q*4+r ----
    if (OUT_F32) {
        float* Ob = (float*)Outv + ((size_t)b * outC + (size_t)mt * 192) * HW_;
#pragma unroll
        for (int mi = 0; mi < 3; mi++)
#pragma unroll
            for (int r = 0; r < 4; r++) {
                int o = w * 48 + mi * 16 + q * 4 + r;
                float4 vv;
                vv.x = acc[mi][0][r]; vv.y = acc[mi][1][r];
                vv.z = acc[mi][2][r]; vv.w = acc[mi][3][r];
                *(float4*)(Ob + (size_t)o * HW_ + nb + 4 * li) = vv;
            }
    } else {
        unsigned short* Ob = (unsigned short*)Outv + ((size_t)b * outC + (size_t)mt * 192) * HW_;
#pragma unroll
        for (int mi = 0; mi < 3; mi++)
#pragma unroll
            for (int r = 0; r < 4; r++) {
                int o = w * 48 + mi * 16 + q * 4 + r;
                ushort4 u;
                u.x = f2bf(acc[mi][0][r]); u.y = f2bf(acc[mi][1][r]);
                u.z = f2bf(acc[mi][2][r]); u.w = f2bf(acc[mi][3][r]);
                *(ushort4*)(Ob + (size_t)o * HW_ + nb + 4 * li) = u;
            }
    }
}

// ---------------------------------------------------------------------------
// dwconv_v: V = dwconv3x3(tmpKV v-half), bf16 out. grid (H, 6, B);
// thread = (channel c = cg*32 + t>>3, 32-px segment).
// ---------------------------------------------------------------------------
__global__ __launch_bounds__(256) void dwconv_v(
    const __hip_bfloat16* __restrict__ tmpKV, const float* __restrict__ wkv_dw,
    __hip_bfloat16* __restrict__ V)
{
    const int y = blockIdx.x, cg = blockIdx.y, b = blockIdx.z;
    const int t = threadIdx.x;
    const int c = cg * 32 + (t >> 3);
    const int x0 = (t & 7) * 32;
    const unsigned short* base =
        (const unsigned short*)(tmpKV + ((size_t)b * 2 * C_ + C_ + c) * HW_);
    const float* wp = wkv_dw + (size_t)(C_ + c) * 9;
    float wgt[9];
#pragma unroll
    for (int i = 0; i < 9; i++) wgt[i] = wp[i];

    float o[32];
#pragma unroll
    for (int i = 0; i < 32; i++) o[i] = 0.f;

#pragma unroll
    for (int dy = -1; dy <= 1; dy++) {
        int yy = y + dy;
        if ((unsigned)yy >= 256u) continue;
        const unsigned short* r = base + yy * W_;
        float v[34];
        v[0]  = (x0 > 0) ? b2f_us(r[x0 - 1]) : 0.f;
        v[33] = (x0 + 32 < 256) ? b2f_us(r[x0 + 32]) : 0.f;
        const uint4* r4 = (const uint4*)(r + x0);
#pragma unroll
        for (int m = 0; m < 4; m++) {
            uint4 raw = r4[m];
            unsigned u;
            u = raw.x; v[1 + 8*m + 0] = __uint_as_float(u << 16); v[1 + 8*m + 1] = __uint_as_float(u & 0xffff0000u);
            u = raw.y; v[1 + 8*m + 2] = __uint_as_float(u << 16); v[1 + 8*m + 3] = __uint_as_float(u & 0xffff0000u);
            u = raw.z; v[1 + 8*m + 4] = __uint_as_float(u << 16); v[1 + 8*m + 5] = __uint_as_float(u & 0xffff0000u);
            u = raw.w; v[1 + 8*m + 6] = __uint_as_float(u << 16); v[1 + 8*m + 7] = __uint_as_float(u & 0xffff0000u);
        }
        float w0 = wgt[3 * (dy + 1) + 0];
        float w1 = wgt[3 * (dy + 1) + 1];
        float w2 = wgt[3 * (dy + 1) + 2];
#pragma unroll
        for (int i = 0; i < 32; i++)
            o[i] += v[i] * w0 + v[i + 1] * w1 + v[i + 2] * w2;
    }
    unsigned short* dst = (unsigned short*)V + ((size_t)b * C_ + c) * HW_ + y * W_ + x0;
#pragma unroll
    for (int m = 0; m < 4; m++) {
        uint4 pk;
        pk.x = (unsigned)f2bf(o[8*m + 0]) | ((unsigned)f2bf(o[8*m + 1]) << 16);
        pk.y = (unsigned)f2bf(o[8*m + 2]) | ((unsigned)f2bf(o[8*m + 3]) << 16);
        pk.z = (unsigned)f2bf(o[8*m + 4]) | ((unsigned)f2bf(o[8*m + 5]) << 16);
        pk.w = (unsigned)f2bf(o[8*m + 6]) | ((unsigned)f2bf(o[8*m + 7]) << 16);
        *(uint4*)(dst + 8 * m) = pk;
    }
}

// ---------------------------------------------------------------------------
// K3: per (b, h, row y): dwconv Q,K -> LDS (bf16), Gram via MFMA + norms.
// Conv: 384 units (2 tensors x 24 ch x 8 segs) over 256 threads.
// Gram: wave w owns output tile (tr,tc)=(w>>1,w&1) of the 24x24 (padded to
// 32x32) Gram; 8 x mfma_f32_16x16x32_bf16 over the 256 pixels; atomicAdd
// valid entries straight to G. Norms (f32, pre-rounding) via LDS atomics.
// LDS pitch 264 bf16 (528 B): ds_read_b128 of 16 rows -> 2-way (free).
// ---------------------------------------------------------------------------
#define PADB 264
__global__ __launch_bounds__(256) void dw_qk_gram(
    const __hip_bfloat16* __restrict__ tmpQ,
    const __hip_bfloat16* __restrict__ tmpKV,
    const float* __restrict__ wq_dw, const float* __restrict__ wkv_dw,
    float* __restrict__ G, float* __restrict__ sq, float* __restrict__ sk)
{
    const int y = blockIdx.x, h = blockIdx.y, b = blockIdx.z;
    const int t = threadIdx.x;

    __shared__ unsigned short Qs[CH_ * PADB];   // 12672 B
    __shared__ unsigned short Ks[CH_ * PADB];   // 12672 B
    __shared__ float sqs[CH_], sks[CH_];

    if (t < CH_) { sqs[t] = 0.f; sks[t] = 0.f; }
    __syncthreads();

    // ---- conv phase: unit u = tens*192 + c*8 + seg ----
    for (int u = t; u < 384; u += 256) {
        const int tens = (u >= 192);
        const int rem = u - tens * 192;
        const int c = rem >> 3;
        const int x0 = (rem & 7) * 32;
        const unsigned short* base = tens
            ? (const unsigned short*)(tmpKV + ((size_t)b * 2 * C_ + h * CH_ + c) * HW_)
            : (const unsigned short*)(tmpQ  + ((size_t)b * C_     + h * CH_ + c) * HW_);
        const float* wp = (tens ? wkv_dw : wq_dw) + (size_t)(h * CH_ + c) * 9;

        float o[32];
#pragma unroll
        for (int i = 0; i < 32; i++) o[i] = 0.f;

#pragma unroll
        for (int dy = -1; dy <= 1; dy++) {
            int yy = y + dy;
            if ((unsigned)yy >= 256u) continue;
            const unsigned short* r = base + yy * W_;
            float v[34];
            v[0]  = (x0 > 0) ? b2f_us(r[x0 - 1]) : 0.f;
            v[33] = (x0 + 32 < 256) ? b2f_us(r[x0 + 32]) : 0.f;
            const uint4* r4 = (const uint4*)(r + x0);
#pragma unroll
            for (int m = 0; m < 4; m++) {
                uint4 raw = r4[m];
                unsigned uu;
                uu = raw.x; v[1 + 8*m + 0] = __uint_as_float(uu << 16); v[1 + 8*m + 1] = __uint_as_float(uu & 0xffff0000u);
                uu = raw.y; v[1 + 8*m + 2] = __uint_as_float(uu << 16); v[1 + 8*m + 3] = __uint_as_float(uu & 0xffff0000u);
                uu = raw.z; v[1 + 8*m + 4] = __uint_as_float(uu << 16); v[1 + 8*m + 5] = __uint_as_float(uu & 0xffff0000u);
                uu = raw.w; v[1 + 8*m + 6] = __uint_as_float(uu << 16); v[1 + 8*m + 7] = __uint_as_float(uu & 0xffff0000u);
            }
            float w0 = wp[3 * (dy + 1) + 0];
            float w1 = wp[3 * (dy + 1) + 1];
            float w2 = wp[3 * (dy + 1) + 2];
#pragma unroll
            for (int i = 0; i < 32; i++)
                o[i] += v[i] * w0 + v[i + 1] * w1 + v[i + 2] * w2;
        }

        // norm contribution (f32, pre-rounding)
        float s = 0.f;
#pragma unroll
        for (int i = 0; i < 32; i++) s += o[i] * o[i];
        atomicAdd(tens ? &sks[c] : &sqs[c], s);

        // pack -> bf16 LDS
        unsigned short* dst = (tens ? Ks : Qs) + c * PADB + x0;
#pragma unroll
        for (int m = 0; m < 4; m++) {
            uint4 pk;
            pk.x = (unsigned)f2bf(o[8*m + 0]) | ((unsigned)f2bf(o[8*m + 1]) << 16);
            pk.y = (unsigned)f2bf(o[8*m + 2]) | ((unsigned)f2bf(o[8*m + 3]) << 16);
            pk.z = (unsigned)f2bf(o[8*m + 4]) | ((unsigned)f2bf(o[8*m + 5]) << 16);
            pk.w = (unsigned)f2bf(o[8*m + 6]) | ((unsigned)f2bf(o[8*m + 7]) << 16);
            *(uint4*)(dst + 8 * m) = pk;
        }
    }
    __syncthreads();

    // ---- norms out ----
    if (t < CH_) {
        atomicAdd(&sq[b * C_ + h * CH_ + t], sqs[t]);
        atomicAdd(&sk[b * C_ + h * CH_ + t], sks[t]);
    }

    // ---- Gram via MFMA: wave w -> 16x16 tile (tr, tc) ----
    const int w = t >> 6, l = t & 63, li = l & 15, q = l >> 4;
    const int tr = w >> 1, tc = w & 1;
    int ar = tr * 16 + li; if (ar > 23) ar = 23;   // clamp: results discarded
    int br = tc * 16 + li; if (br > 23) br = 23;
    const unsigned short* arow = &Qs[ar * PADB];
    const unsigned short* brow = &Ks[br * PADB];

    f32x4 acc = (f32x4){0.f, 0.f, 0.f, 0.f};
#pragma unroll
    for (int ks = 0; ks < 8; ks++) {
        bf16x8 af = *(const bf16x8*)&arow[ks * 32 + q * 8];
        bf16x8 bf = *(const bf16x8*)&brow[ks * 32 + q * 8];
        acc = __builtin_amdgcn_mfma_f32_16x16x32_bf16(af, bf, acc, 0, 0, 0);
    }

    float* Gb = G + (size_t)(b * HEADS_ + h) * CH_ * CH_;
    const int col = tc * 16 + li;
    if (col < CH_) {
#pragma unroll
        for (int r = 0; r < 4; r++) {
            int row = tr * 16 + q * 4 + r;
            if (row < CH_)
                atomicAdd(&Gb[row * CH_ + col], acc[r]);
        }
    }
}

// K4: normalize G, softmax, compose M
__global__ __launch_bounds__(192) void softmax_proj(
    const float* __restrict__ G, const float* __restrict__ sq,
    const float* __restrict__ sk, const float* __restrict__ temperature,
    const float* __restrict__ wproj, float* __restrict__ M)
{
    const int h = blockIdx.x, b = blockIdx.y, t = threadIdx.x;
    __shared__ float attn[CH_][CH_];
    __shared__ float rk[CH_];
    const float* Gb = G + (size_t)(b * HEADS_ + h) * CH_ * CH_;
    if (t < CH_)
        rk[t] = 1.f / fmaxf(sqrtf(sk[b * C_ + h * CH_ + t]), 1e-12f);
    __syncthreads();
    if (t < CH_) {
        float rq = 1.f / fmaxf(sqrtf(sq[b * C_ + h * CH_ + t]), 1e-12f);
        float tempv = temperature[h];
        float row[CH_];
        float mx = -1e30f;
        for (int d = 0; d < CH_; d++) {
            row[d] = Gb[t * CH_ + d] * rq * rk[d] * tempv;
            mx = fmaxf(mx, row[d]);
        }
        float s = 0.f;
        for (int d = 0; d < CH_; d++) { row[d] = __expf(row[d] - mx); s += row[d]; }
        float inv = 1.f / s;
        for (int d = 0; d < CH_; d++) attn[t][d] = row[d] * inv;
    }
    __syncthreads();
    const int o = t;
    float wrow[CH_];
    for (int c = 0; c < CH_; c++) wrow[c] = wproj[o * C_ + h * CH_ + c];
    for (int d = 0; d < CH_; d++) {
        float s = 0.f;
        for (int c = 0; c < CH_; c++) s += wrow[c] * attn[c][d];
        M[((size_t)b * C_ + o) * C_ + h * CH_ + d] = s;
    }
}

extern "C" void kernel_launch(void* const* d_in, const int* in_sizes, int n_in,
                              void* d_out, int out_size, void* d_ws, size_t ws_size,
                              hipStream_t stream)
{
    const float* x           = (const float*)d_in[0];
    const float* x_ref       = (const float*)d_in[1];
    const float* wq          = (const float*)d_in[2];
    const float* wq_dw       = (const float*)d_in[3];
    const float* wkv         = (const float*)d_in[4];
    const float* wkv_dw      = (const float*)d_in[5];
    const float* wproj       = (const float*)d_in[6];
    const float* temperature = (const float*)d_in[7];
    float* out = (float*)d_out;

    char* ws = (char*)d_ws;
    __hip_bfloat16* tmpQ  = (__hip_bfloat16*)(ws);
    __hip_bfloat16* tmpKV = (__hip_bfloat16*)(ws + 50331648);
    __hip_bfloat16* tmpV  = (__hip_bfloat16*)(ws);          // aliases tmpQ (safe: K3 before dwconv_v)
    float* G  = (float*)(ws + 150994944);
    float* sq = (float*)(ws + 151031808);
    float* sk = (float*)(ws + 151033344);
    float* M  = (float*)(ws + 151034880);

    hipMemsetAsync(G, 0, 36864 + 1536 + 1536, stream);

    // K1: q1x1 = wq @ x          -> tmpQ (bf16)
    gemm_mfma<true, false><<<dim3(HW_ / 64, 1, B_), 256, 0, stream>>>(
        wq, 0, x, tmpQ, 192);
    // K2: kv1x1 = wkv @ x_ref    -> tmpKV (bf16)
    gemm_mfma<true, false><<<dim3(HW_ / 64, 2, B_), 256, 0, stream>>>(
        wkv, 0, x_ref, tmpKV, 384);
    // K3: dwconv q,k + gram (MFMA) + norms
    dw_qk_gram<<<dim3(H_, HEADS_, B_), 256, 0, stream>>>(
        tmpQ, tmpKV, wq_dw, wkv_dw, G, sq, sk);
    // K4: softmax + compose M
    softmax_proj<<<dim3(HEADS_, B_), 192, 0, stream>>>(
        G, sq, sk, temperature, wproj, M);
    // dwconv of V (overwrites tmpQ region)
    dwconv_v<<<dim3(H_, 6, B_), 256, 0, stream>>>(tmpKV, wkv_dw, tmpV);
    // K5: out = M @ V            -> out (f32)
    gemm_mfma<false, true><<<dim3(HW_ / 64, 1, B_), 256, 0, stream>>>(
        M, 192 * 192, tmpV, out, 192);
}

// Round 2
// 434.591 us; speedup vs baseline: 1.3072x; 1.0771x over previous
//
#include <hip/hip_runtime.h>
#include <hip/hip_bf16.h>

#define B_ 2
#define C_ 192
#define HEADS_ 8
#define CH_ 24
#define H_ 256
#define W_ 256
#define HW_ 65536

// ---------------- workspace layout (bytes) ----------------
// tmpQ  bf16 [B][192][HW]   @ 0           (50331648)   } tmpV aliases tmpQ
// tmpKV bf16 [B][384][HW]   @ 50331648    (100663296)  } (K3 consumes tmpQ first)
// G     f32  [B][8][24][24] @ 150994944   (36864)
// sq    f32  [B][192]       @ 151031808   (1536)
// sk    f32  [B][192]       @ 151033344   (1536)
// wqbf  bf16 [192][192]     @ 151034880   (73728)   } Mbf aliases wqbf
// wkvbf bf16 [384][192]     @ 151108608   (147456)  } (both dead before K4)
// Mbf   bf16 [B][192][192]  @ 151034880   (147456)

using bf16x8 = __attribute__((ext_vector_type(8))) __bf16;
using f32x4  = __attribute__((ext_vector_type(4))) float;

__device__ __forceinline__ float b2f_us(unsigned short u) {
    return __uint_as_float(((unsigned)u) << 16);
}
__device__ __forceinline__ unsigned short f2bf(float f) {
    union { __hip_bfloat16 b; unsigned short u; } cv;
    cv.b = __float2bfloat16(f);
    return cv.u;
}

// ---------------------------------------------------------------------------
// convert_w: one-shot f32->bf16 of wq (192x192) and wkv (384x192).
// grid 108 x 256: quad i < 9216 -> wq, else wkv.
// ---------------------------------------------------------------------------
__global__ __launch_bounds__(256) void convert_w(
    const float* __restrict__ wq, const float* __restrict__ wkv,
    unsigned short* __restrict__ wqbf, unsigned short* __restrict__ wkvbf)
{
    int i = blockIdx.x * 256 + threadIdx.x;   // quad index, total 27648
    const float* src; unsigned short* dst; int qd;
    if (i < 9216) { src = wq;  dst = wqbf;  qd = i; }
    else          { src = wkv; dst = wkvbf; qd = i - 9216; }
    float4 v = *(const float4*)(src + (size_t)qd * 4);
    ushort4 u;
    u.x = f2bf(v.x); u.y = f2bf(v.y); u.z = f2bf(v.z); u.w = f2bf(v.w);
    *(ushort4*)(dst + (size_t)qd * 4) = u;
}

// ---------------------------------------------------------------------------
// MFMA GEMM: Out[o, n] = sum_k A[o, k] * B[k, n];  K = 192, N-tile = 64,
// M-tile = 192 (4 waves x 48 rows). A pre-converted bf16 (tiny, L2-hot).
// B either fp32 (x / x_ref) or bf16 (tmpV). Out bf16 or f32.
// LDS: Al[o][k] pitch 40 bf16; Bl[rB][k] pitch 40, rB = ((p&3)<<4)|(p>>2)
// so lane li's 4 n-frags are pixels 4*li .. 4*li+3 (contiguous epilogue).
// ---------------------------------------------------------------------------
template<bool B_F32, bool OUT_F32>
__global__ __launch_bounds__(256) void gemm_mfma(
    const unsigned short* __restrict__ A, long a_bstride,
    const void* __restrict__ Bv, void* __restrict__ Outv, int outC)
{
    const int nb = blockIdx.x * 64;
    const int mt = blockIdx.y;
    const int b  = blockIdx.z;
    const int t  = threadIdx.x;

    __shared__ unsigned short Al[192 * 40];
    __shared__ unsigned short Bl[64 * 40];

    const unsigned short* Ab = A + (size_t)b * a_bstride + (size_t)mt * 192 * 192;

    const int w = t >> 6, l = t & 63, li = l & 15, q = l >> 4;

    f32x4 acc[3][4];
#pragma unroll
    for (int mi = 0; mi < 3; mi++)
#pragma unroll
        for (int ni = 0; ni < 4; ni++)
            acc[mi][ni] = (f32x4){0.f, 0.f, 0.f, 0.f};

    const int p0 = (t & 15) * 4;   // B staging: pixel group
    const int kp = t >> 4;         // B staging: k-pair index (0..15)

    for (int kc = 0; kc < 6; kc++) {
        const int k0 = kc * 32;

        // ---- stage A chunk: 192 x 32 bf16, plain 16B copies ----
#pragma unroll
        for (int j = 0; j < 3; j++) {
            int e = t + 256 * j;            // 0..767
            int o = e >> 2, kq = e & 3;
            *(uint4*)&Al[o * 40 + kq * 8] =
                *(const uint4*)(Ab + (size_t)o * 192 + k0 + kq * 8);
        }

        // ---- stage B chunk: 32 x 64, transposed into Bl[rB][k] ----
        {
            const int k = k0 + kp * 2;
            unsigned int packed[4];
            if (B_F32) {
                const float* Bb = (const float*)Bv + (size_t)b * 192 * HW_;
                float4 r0 = *(const float4*)(Bb + (size_t)k * HW_ + nb + p0);
                float4 r1 = *(const float4*)(Bb + (size_t)(k + 1) * HW_ + nb + p0);
                packed[0] = (unsigned)f2bf(r0.x) | ((unsigned)f2bf(r1.x) << 16);
                packed[1] = (unsigned)f2bf(r0.y) | ((unsigned)f2bf(r1.y) << 16);
                packed[2] = (unsigned)f2bf(r0.z) | ((unsigned)f2bf(r1.z) << 16);
                packed[3] = (unsigned)f2bf(r0.w) | ((unsigned)f2bf(r1.w) << 16);
            } else {
                const unsigned short* Bb = (const unsigned short*)Bv + (size_t)b * 192 * HW_;
                ushort4 r0 = *(const ushort4*)(Bb + (size_t)k * HW_ + nb + p0);
                ushort4 r1 = *(const ushort4*)(Bb + (size_t)(k + 1) * HW_ + nb + p0);
                packed[0] = (unsigned)r0.x | ((unsigned)r1.x << 16);
                packed[1] = (unsigned)r0.y | ((unsigned)r1.y << 16);
                packed[2] = (unsigned)r0.z | ((unsigned)r1.z << 16);
                packed[3] = (unsigned)r0.w | ((unsigned)r1.w << 16);
            }
#pragma unroll
            for (int c = 0; c < 4; c++) {
                int p = p0 + c;
                int rB = ((p & 3) << 4) | (p >> 2);
                *(unsigned int*)&Bl[rB * 40 + kp * 2] = packed[c];
            }
        }
        __syncthreads();

        // ---- fragments + MFMA ----
        bf16x8 af[3], bfr[4];
#pragma unroll
        for (int mi = 0; mi < 3; mi++)
            af[mi] = *(const bf16x8*)&Al[(w * 48 + mi * 16 + li) * 40 + q * 8];
#pragma unroll
        for (int ni = 0; ni < 4; ni++)
            bfr[ni] = *(const bf16x8*)&Bl[(ni * 16 + li) * 40 + q * 8];
#pragma unroll
        for (int mi = 0; mi < 3; mi++)
#pragma unroll
            for (int ni = 0; ni < 4; ni++)
                acc[mi][ni] = __builtin_amdgcn_mfma_f32_16x16x32_bf16(
                    af[mi], bfr[ni], acc[mi][ni], 0, 0, 0);
        __syncthreads();
    }

    // ---- epilogue: lane li holds pixels nb+4*li .. +3 (regs ni), rows q*4+r ----
    if (OUT_F32) {
        float* Ob = (float*)Outv + ((size_t)b * outC + (size_t)mt * 192) * HW_;
#pragma unroll
        for (int mi = 0; mi < 3; mi++)
#pragma unroll
            for (int r = 0; r < 4; r++) {
                int o = w * 48 + mi * 16 + q * 4 + r;
                float4 vv;
                vv.x = acc[mi][0][r]; vv.y = acc[mi][1][r];
                vv.z = acc[mi][2][r]; vv.w = acc[mi][3][r];
                *(float4*)(Ob + (size_t)o * HW_ + nb + 4 * li) = vv;
            }
    } else {
        unsigned short* Ob = (unsigned short*)Outv + ((size_t)b * outC + (size_t)mt * 192) * HW_;
#pragma unroll
        for (int mi = 0; mi < 3; mi++)
#pragma unroll
            for (int r = 0; r < 4; r++) {
                int o = w * 48 + mi * 16 + q * 4 + r;
                ushort4 u;
                u.x = f2bf(acc[mi][0][r]); u.y = f2bf(acc[mi][1][r]);
                u.z = f2bf(acc[mi][2][r]); u.w = f2bf(acc[mi][3][r]);
                *(ushort4*)(Ob + (size_t)o * HW_ + nb + 4 * li) = u;
            }
    }
}

// ---------------------------------------------------------------------------
// dwconv_v: V = dwconv3x3(tmpKV v-half), bf16 out. grid (H, 6, B);
// thread = (channel c = cg*32 + t>>3, 32-px segment).
// ---------------------------------------------------------------------------
__global__ __launch_bounds__(256) void dwconv_v(
    const __hip_bfloat16* __restrict__ tmpKV, const float* __restrict__ wkv_dw,
    __hip_bfloat16* __restrict__ V)
{
    const int y = blockIdx.x, cg = blockIdx.y, b = blockIdx.z;
    const int t = threadIdx.x;
    const int c = cg * 32 + (t >> 3);
    const int x0 = (t & 7) * 32;
    const unsigned short* base =
        (const unsigned short*)(tmpKV + ((size_t)b * 2 * C_ + C_ + c) * HW_);
    const float* wp = wkv_dw + (size_t)(C_ + c) * 9;
    float wgt[9];
#pragma unroll
    for (int i = 0; i < 9; i++) wgt[i] = wp[i];

    float o[32];
#pragma unroll
    for (int i = 0; i < 32; i++) o[i] = 0.f;

#pragma unroll
    for (int dy = -1; dy <= 1; dy++) {
        int yy = y + dy;
        if ((unsigned)yy >= 256u) continue;
        const unsigned short* r = base + yy * W_;
        float v[34];
        v[0]  = (x0 > 0) ? b2f_us(r[x0 - 1]) : 0.f;
        v[33] = (x0 + 32 < 256) ? b2f_us(r[x0 + 32]) : 0.f;
        const uint4* r4 = (const uint4*)(r + x0);
#pragma unroll
        for (int m = 0; m < 4; m++) {
            uint4 raw = r4[m];
            unsigned u;
            u = raw.x; v[1 + 8*m + 0] = __uint_as_float(u << 16); v[1 + 8*m + 1] = __uint_as_float(u & 0xffff0000u);
            u = raw.y; v[1 + 8*m + 2] = __uint_as_float(u << 16); v[1 + 8*m + 3] = __uint_as_float(u & 0xffff0000u);
            u = raw.z; v[1 + 8*m + 4] = __uint_as_float(u << 16); v[1 + 8*m + 5] = __uint_as_float(u & 0xffff0000u);
            u = raw.w; v[1 + 8*m + 6] = __uint_as_float(u << 16); v[1 + 8*m + 7] = __uint_as_float(u & 0xffff0000u);
        }
        float w0 = wgt[3 * (dy + 1) + 0];
        float w1 = wgt[3 * (dy + 1) + 1];
        float w2 = wgt[3 * (dy + 1) + 2];
#pragma unroll
        for (int i = 0; i < 32; i++)
            o[i] += v[i] * w0 + v[i + 1] * w1 + v[i + 2] * w2;
    }
    unsigned short* dst = (unsigned short*)V + ((size_t)b * C_ + c) * HW_ + y * W_ + x0;
#pragma unroll
    for (int m = 0; m < 4; m++) {
        uint4 pk;
        pk.x = (unsigned)f2bf(o[8*m + 0]) | ((unsigned)f2bf(o[8*m + 1]) << 16);
        pk.y = (unsigned)f2bf(o[8*m + 2]) | ((unsigned)f2bf(o[8*m + 3]) << 16);
        pk.z = (unsigned)f2bf(o[8*m + 4]) | ((unsigned)f2bf(o[8*m + 5]) << 16);
        pk.w = (unsigned)f2bf(o[8*m + 6]) | ((unsigned)f2bf(o[8*m + 7]) << 16);
        *(uint4*)(dst + 8 * m) = pk;
    }
}

// ---------------------------------------------------------------------------
// K3: per (b, h, y-group of 4 rows): dwconv Q,K -> LDS (bf16), Gram via MFMA
// accumulated in registers across the 4 rows, + norms. Atomics once per block
// (4x fewer than per-row): contention on G drops from 256- to 64-way.
// Conv: 384 units (2 tensors x 24 ch x 8 segs) over 256 threads.
// Gram: wave w owns 16x16 tile (tr,tc) of the 24x24 (padded) Gram.
// LDS pitch 264 bf16 (528 B): ds_read_b128 of 16 rows -> 2-way (free).
// ---------------------------------------------------------------------------
#define PADB 264
#define YG 4
__global__ __launch_bounds__(256) void dw_qk_gram(
    const __hip_bfloat16* __restrict__ tmpQ,
    const __hip_bfloat16* __restrict__ tmpKV,
    const float* __restrict__ wq_dw, const float* __restrict__ wkv_dw,
    float* __restrict__ G, float* __restrict__ sq, float* __restrict__ sk)
{
    const int y0 = blockIdx.x * YG, h = blockIdx.y, b = blockIdx.z;
    const int t = threadIdx.x;

    __shared__ unsigned short Qs[CH_ * PADB];   // 12672 B
    __shared__ unsigned short Ks[CH_ * PADB];   // 12672 B
    __shared__ float sqs[CH_], sks[CH_];

    if (t < CH_) { sqs[t] = 0.f; sks[t] = 0.f; }

    // Gram fragment geometry (constant per thread)
    const int w = t >> 6, l = t & 63, li = l & 15, q = l >> 4;
    const int tr = w >> 1, tc = w & 1;
    int ar = tr * 16 + li; if (ar > 23) ar = 23;   // clamp: results discarded
    int br = tc * 16 + li; if (br > 23) br = 23;
    const unsigned short* arow = &Qs[ar * PADB];
    const unsigned short* brow = &Ks[br * PADB];
    f32x4 acc = (f32x4){0.f, 0.f, 0.f, 0.f};

    __syncthreads();

    for (int yi = 0; yi < YG; yi++) {
        const int y = y0 + yi;

        // ---- conv phase: unit u = tens*192 + c*8 + seg ----
        for (int u = t; u < 384; u += 256) {
            const int tens = (u >= 192);
            const int rem = u - tens * 192;
            const int c = rem >> 3;
            const int x0 = (rem & 7) * 32;
            const unsigned short* base = tens
                ? (const unsigned short*)(tmpKV + ((size_t)b * 2 * C_ + h * CH_ + c) * HW_)
                : (const unsigned short*)(tmpQ  + ((size_t)b * C_     + h * CH_ + c) * HW_);
            const float* wp = (tens ? wkv_dw : wq_dw) + (size_t)(h * CH_ + c) * 9;

            float o[32];
#pragma unroll
            for (int i = 0; i < 32; i++) o[i] = 0.f;

#pragma unroll
            for (int dy = -1; dy <= 1; dy++) {
                int yy = y + dy;
                if ((unsigned)yy >= 256u) continue;
                const unsigned short* r = base + yy * W_;
                float v[34];
                v[0]  = (x0 > 0) ? b2f_us(r[x0 - 1]) : 0.f;
                v[33] = (x0 + 32 < 256) ? b2f_us(r[x0 + 32]) : 0.f;
                const uint4* r4 = (const uint4*)(r + x0);
#pragma unroll
                for (int m = 0; m < 4; m++) {
                    uint4 raw = r4[m];
                    unsigned uu;
                    uu = raw.x; v[1 + 8*m + 0] = __uint_as_float(uu << 16); v[1 + 8*m + 1] = __uint_as_float(uu & 0xffff0000u);
                    uu = raw.y; v[1 + 8*m + 2] = __uint_as_float(uu << 16); v[1 + 8*m + 3] = __uint_as_float(uu & 0xffff0000u);
                    uu = raw.z; v[1 + 8*m + 4] = __uint_as_float(uu << 16); v[1 + 8*m + 5] = __uint_as_float(uu & 0xffff0000u);
                    uu = raw.w; v[1 + 8*m + 6] = __uint_as_float(uu << 16); v[1 + 8*m + 7] = __uint_as_float(uu & 0xffff0000u);
                }
                float w0 = wp[3 * (dy + 1) + 0];
                float w1 = wp[3 * (dy + 1) + 1];
                float w2 = wp[3 * (dy + 1) + 2];
#pragma unroll
                for (int i = 0; i < 32; i++)
                    o[i] += v[i] * w0 + v[i + 1] * w1 + v[i + 2] * w2;
            }

            // norm contribution (f32, pre-rounding)
            float s = 0.f;
#pragma unroll
            for (int i = 0; i < 32; i++) s += o[i] * o[i];
            atomicAdd(tens ? &sks[c] : &sqs[c], s);

            // pack -> bf16 LDS
            unsigned short* dst = (tens ? Ks : Qs) + c * PADB + x0;
#pragma unroll
            for (int m = 0; m < 4; m++) {
                uint4 pk;
                pk.x = (unsigned)f2bf(o[8*m + 0]) | ((unsigned)f2bf(o[8*m + 1]) << 16);
                pk.y = (unsigned)f2bf(o[8*m + 2]) | ((unsigned)f2bf(o[8*m + 3]) << 16);
                pk.z = (unsigned)f2bf(o[8*m + 4]) | ((unsigned)f2bf(o[8*m + 5]) << 16);
                pk.w = (unsigned)f2bf(o[8*m + 6]) | ((unsigned)f2bf(o[8*m + 7]) << 16);
                *(uint4*)(dst + 8 * m) = pk;
            }
        }
        __syncthreads();

        // ---- Gram via MFMA: accumulate into acc across the YG rows ----
#pragma unroll
        for (int ks = 0; ks < 8; ks++) {
            bf16x8 af = *(const bf16x8*)&arow[ks * 32 + q * 8];
            bf16x8 bf = *(const bf16x8*)&brow[ks * 32 + q * 8];
            acc = __builtin_amdgcn_mfma_f32_16x16x32_bf16(af, bf, acc, 0, 0, 0);
        }
        __syncthreads();   // protect LDS before next conv overwrite
    }

    // ---- norms out ----
    if (t < CH_) {
        atomicAdd(&sq[b * C_ + h * CH_ + t], sqs[t]);
        atomicAdd(&sk[b * C_ + h * CH_ + t], sks[t]);
    }

    // ---- Gram out ----
    float* Gb = G + (size_t)(b * HEADS_ + h) * CH_ * CH_;
    const int col = tc * 16 + li;
    if (col < CH_) {
#pragma unroll
        for (int r = 0; r < 4; r++) {
            int row = tr * 16 + q * 4 + r;
            if (row < CH_)
                atomicAdd(&Gb[row * CH_ + col], acc[r]);
        }
    }
}

// K4: normalize G, softmax, compose M (written directly as bf16)
__global__ __launch_bounds__(192) void softmax_proj(
    const float* __restrict__ G, const float* __restrict__ sq,
    const float* __restrict__ sk, const float* __restrict__ temperature,
    const float* __restrict__ wproj, unsigned short* __restrict__ Mbf)
{
    const int h = blockIdx.x, b = blockIdx.y, t = threadIdx.x;
    __shared__ float attn[CH_][CH_];
    __shared__ float rk[CH_];
    const float* Gb = G + (size_t)(b * HEADS_ + h) * CH_ * CH_;
    if (t < CH_)
        rk[t] = 1.f / fmaxf(sqrtf(sk[b * C_ + h * CH_ + t]), 1e-12f);
    __syncthreads();
    if (t < CH_) {
        float rq = 1.f / fmaxf(sqrtf(sq[b * C_ + h * CH_ + t]), 1e-12f);
        float tempv = temperature[h];
        float row[CH_];
        float mx = -1e30f;
        for (int d = 0; d < CH_; d++) {
            row[d] = Gb[t * CH_ + d] * rq * rk[d] * tempv;
            mx = fmaxf(mx, row[d]);
        }
        float s = 0.f;
        for (int d = 0; d < CH_; d++) { row[d] = __expf(row[d] - mx); s += row[d]; }
        float inv = 1.f / s;
        for (int d = 0; d < CH_; d++) attn[t][d] = row[d] * inv;
    }
    __syncthreads();
    const int o = t;
    float wrow[CH_];
    for (int c = 0; c < CH_; c++) wrow[c] = wproj[o * C_ + h * CH_ + c];
    for (int d = 0; d < CH_; d++) {
        float s = 0.f;
        for (int c = 0; c < CH_; c++) s += wrow[c] * attn[c][d];
        Mbf[((size_t)b * C_ + o) * C_ + h * CH_ + d] = f2bf(s);
    }
}

extern "C" void kernel_launch(void* const* d_in, const int* in_sizes, int n_in,
                              void* d_out, int out_size, void* d_ws, size_t ws_size,
                              hipStream_t stream)
{
    const float* x           = (const float*)d_in[0];
    const float* x_ref       = (const float*)d_in[1];
    const float* wq          = (const float*)d_in[2];
    const float* wq_dw       = (const float*)d_in[3];
    const float* wkv         = (const float*)d_in[4];
    const float* wkv_dw      = (const float*)d_in[5];
    const float* wproj       = (const float*)d_in[6];
    const float* temperature = (const float*)d_in[7];
    float* out = (float*)d_out;

    char* ws = (char*)d_ws;
    __hip_bfloat16* tmpQ  = (__hip_bfloat16*)(ws);
    __hip_bfloat16* tmpKV = (__hip_bfloat16*)(ws + 50331648);
    __hip_bfloat16* tmpV  = (__hip_bfloat16*)(ws);          // aliases tmpQ (safe: K3 before dwconv_v)
    float* G  = (float*)(ws + 150994944);
    float* sq = (float*)(ws + 151031808);
    float* sk = (float*)(ws + 151033344);
    unsigned short* wqbf  = (unsigned short*)(ws + 151034880);
    unsigned short* wkvbf = (unsigned short*)(ws + 151108608);
    unsigned short* Mbf   = (unsigned short*)(ws + 151034880);  // aliases wqbf (dead by K4)

    hipMemsetAsync(G, 0, 36864 + 1536 + 1536, stream);

    // K0: weights -> bf16 (once, not per GEMM block)
    convert_w<<<dim3(108), 256, 0, stream>>>(wq, wkv, wqbf, wkvbf);
    // K1: q1x1 = wq @ x          -> tmpQ (bf16)
    gemm_mfma<true, false><<<dim3(HW_ / 64, 1, B_), 256, 0, stream>>>(
        wqbf, 0, x, tmpQ, 192);
    // K2: kv1x1 = wkv @ x_ref    -> tmpKV (bf16)
    gemm_mfma<true, false><<<dim3(HW_ / 64, 2, B_), 256, 0, stream>>>(
        wkvbf, 0, x_ref, tmpKV, 384);
    // K3: dwconv q,k + gram (MFMA, y-grouped) + norms
    dw_qk_gram<<<dim3(H_ / YG, HEADS_, B_), 256, 0, stream>>>(
        tmpQ, tmpKV, wq_dw, wkv_dw, G, sq, sk);
    // K4: softmax + compose M (bf16)
    softmax_proj<<<dim3(HEADS_, B_), 192, 0, stream>>>(
        G, sq, sk, temperature, wproj, Mbf);
    // dwconv of V (overwrites tmpQ region)
    dwconv_v<<<dim3(H_, 6, B_), 256, 0, stream>>>(tmpKV, wkv_dw, tmpV);
    // K5: out = M @ V            -> out (f32)
    gemm_mfma<false, true><<<dim3(HW_ / 64, 1, B_), 256, 0, stream>>>(
        Mbf, 192 * 192, tmpV, out, 192);
}